// Round 1
// baseline (2272.396 us; speedup 1.0000x reference)
//
#include <hip/hip_runtime.h>
#include <cmath>

#define GXN 240
#define GYN 121
#define SP  29040   // GXN*GYN
#define NB  8
#define NCH 213
#define EPSV 1e-6f
#define DMAXF 7.75f   // sqrt(2*30) * ls  -> weight >= ~9.4e-14 kept
#define ACLIP -30.0f

__device__ __forceinline__ float gxv(int i){ return (float)i * (1.0f/239.0f); }
__device__ __forceinline__ float gyv(int j){ return -0.25f + (float)j * (1.0f/240.0f); }
__device__ __forceinline__ size_t oidx(int b,int c,int i,int j){
  return (((size_t)b*NCH + c)*GXN + i)*GYN + j;
}
__device__ __forceinline__ int lbnd(const float* a, int n, float v){
  int lo=0, hi=n;
  while(lo<hi){ int m=(lo+hi)>>1; if(a[m]<v) lo=m+1; else hi=m; }
  return lo;
}
__device__ __forceinline__ int ubnd(const float* a, int n, float v){
  int lo=0, hi=n;
  while(lo<hi){ int m=(lo+hi)>>1; if(a[m]<=v) lo=m+1; else hi=m; }
  return lo;
}

// ---------------- zero the atomic-accumulated channel ranges ----------------
__global__ void kzero_range(float* __restrict__ out, int chBase, int nch){
  long long idx = (long long)blockIdx.x*blockDim.x + threadIdx.x;
  long long tot = (long long)NB*nch*SP;
  if(idx>=tot) return;
  int b = (int)(idx/((long long)nch*SP));
  long long off = idx - (long long)b*nch*SP;
  out[oidx(b,chBase,0,0) + off] = 0.f;
}

// ---------------- IASI / ASCAT: nan->0, nearest resize, flip lat ------------
template<int C>
__global__ void kresize(const float* __restrict__ src, float* __restrict__ out, int chBase){
  int idx = blockIdx.x*blockDim.x + threadIdx.x;
  if(idx >= NB*C*SP) return;
  int j = idx%GYN; int i=(idx/GYN)%GXN; int c=(idx/SP)%C; int b=idx/(SP*C);
  int hi = i>>1;                       // (i*120)//240
  int wi = ((120 - j)*60)/121;         // flip j then (j'*60)//121
  float v = src[((b*120 + hi)*60 + wi)*C + c];
  if(!isfinite(v)) v = isnan(v) ? 0.f : (v>0.f? 3.4028235e38f : -3.4028235e38f);
  out[oidx(b,chBase+c,i,j)] = v;
}

// ---------------- elevation: out[b,183,i,j] = era5[b,0,2i,241-2j] -----------
__global__ void kelev(const float* __restrict__ e, float* __restrict__ out){
  int idx = blockIdx.x*blockDim.x + threadIdx.x;
  if(idx>=NB*SP) return;
  int j=idx%GYN; int i=(idx/GYN)%GXN; int b=idx/SP;
  out[oidx(b,183,i,j)] = e[(b*480 + 2*i)*242 + (241 - 2*j)];
}

// ---------------- climatology copy + aux_time broadcast ---------------------
__global__ void kclim(const float* __restrict__ clim, const float* __restrict__ aux,
                      float* __restrict__ out){
  int idx = blockIdx.x*blockDim.x + threadIdx.x;
  if(idx >= NB*29*SP) return;
  int j=idx%GYN; int i=(idx/GYN)%GXN; int c=(idx/SP)%29; int b=idx/(SP*29);
  float v;
  if(c<24) v = clim[(((size_t)b*24 + c)*GXN + i)*GYN + j];
  else     v = aux[b*5 + (c-24)];
  out[oidx(b,184+c,i,j)] = v;
}

// ---------------- off-grid setconv: scatter with atomics --------------------
// y layout: y[(b*C + c)*N + n]; px/py: per-b stride cstride
template<int C>
__global__ void koff(const float* __restrict__ px, const float* __restrict__ py, int cstride,
                     const float* __restrict__ y, int N, int chBase,
                     const float* __restrict__ lsp, float* __restrict__ out){
  int idx = blockIdx.x*blockDim.x + threadIdx.x;
  if(idx >= NB*N) return;
  int b = idx/N, n = idx%N;
  float ls = lsp[0];
  float inv2 = 0.5f/(ls*ls);
  float dmax = DMAXF*ls;
  float x  = px[(size_t)b*cstride + n];
  float yy = py[(size_t)b*cstride + n];
  float yv[C]; bool mv[C];
#pragma unroll
  for(int c=0;c<C;c++){
    float v = y[((size_t)b*C + c)*N + n];
    mv[c] = isfinite(v);
    yv[c] = mv[c]? v : 0.f;
  }
  float ci = x*239.0f,          kmx = dmax*239.0f;
  int ilo = (int)ceilf(ci-kmx); if(ilo<0) ilo=0;
  int ihi = (int)floorf(ci+kmx); if(ihi>GXN-1) ihi=GXN-1;
  float cj = (yy+0.25f)*240.0f, kmy = dmax*240.0f;
  int jlo = (int)ceilf(cj-kmy); if(jlo<0) jlo=0;
  int jhi = (int)floorf(cj+kmy); if(jhi>GYN-1) jhi=GYN-1;
  for(int i=ilo;i<=ihi;i++){
    float dx = x - gxv(i);
    float ax = -dx*dx*inv2;
    if(ax<ACLIP) continue;
    for(int jj=jlo;jj<=jhi;jj++){
      float dy = yy - gyv(jj);
      float a = ax - dy*dy*inv2;
      if(a<ACLIP) continue;
      float wt = expf(a);
      float* o = out + oidx(b,chBase,i,jj);
#pragma unroll
      for(int c=0;c<C;c++){
        if(mv[c]){
          atomicAdd(o + (size_t)(2*c)*SP,   wt);
          atomicAdd(o + (size_t)(2*c+1)*SP, wt*yv[c]);
        }
      }
    }
  }
}

// finalize: sig /= den+eps for C (den,sig) channel pairs starting at chBase
__global__ void kdiv(float* __restrict__ out, int chBase, int C){
  int idx = blockIdx.x*blockDim.x + threadIdx.x;
  if(idx >= NB*C*SP) return;
  int j=idx%GYN; int i=(idx/GYN)%GXN; int c=(idx/SP)%C; int b=idx/(SP*C);
  size_t d = oidx(b, chBase + 2*c, i, j);
  out[d + SP] = out[d + SP]/(out[d] + EPSV);
}

// ---------------- on-grid setconv: gather per output cell -------------------
// MODE 0: val = src[((b*C+c)*H + h)*W + w], mask = isfinite            (GRIDSAT)
// MODE 1: val = src[((b*W+w)*H + h)*C + c], mask = fin && v!=0 && c!=C-1 (AMSU-A)
// MODE 2: val = src[((b*H+h)*W + w)*C + c], mask = fin && v!=0          (AMSU-B/HIRS)
template<int C, int MODE>
__global__ void kon(const float* __restrict__ xlon, const float* __restrict__ xlat,
                    const float* __restrict__ src, int H, int W, int chBase,
                    const float* __restrict__ lsp, float* __restrict__ out){
  int idx = blockIdx.x*blockDim.x + threadIdx.x;
  if(idx >= NB*SP) return;
  int j=idx%GYN; int i=(idx/GYN)%GXN; int b=idx/SP;
  float ls = lsp[0];
  float inv2 = 0.5f/(ls*ls);
  float dmax = DMAXF*ls;
  float gi = gxv(i), gj = gyv(j);
  const float* lon = xlon + b*H;
  const float* lat = xlat + b*W;
  int hlo = lbnd(lon,H,gi-dmax), hhi = ubnd(lon,H,gi+dmax);
  int wlo = lbnd(lat,W,gj-dmax), whi = ubnd(lat,W,gj+dmax);
  float den[C], sig[C];
#pragma unroll
  for(int c=0;c<C;c++){ den[c]=0.f; sig[c]=0.f; }
  for(int h=hlo; h<hhi; h++){
    float dx = lon[h]-gi;
    float ax = -dx*dx*inv2;
    if(ax < ACLIP) continue;
    for(int w=wlo; w<whi; w++){
      float dy = lat[w]-gj;
      float a = ax - dy*dy*inv2;
      if(a < ACLIP) continue;
      float wt = expf(a);
      const float* s;
      if(MODE==0)      s = src + ((size_t)b*C*H + h)*W + w;
      else if(MODE==1) s = src + (((size_t)b*W + w)*H + h)*C;
      else             s = src + (((size_t)b*H + h)*W + w)*C;
#pragma unroll
      for(int c=0;c<C;c++){
        float v = (MODE==0) ? s[(size_t)c*H*W] : s[c];
        bool ok = isfinite(v);
        if(MODE>=1) ok = ok && (v!=0.0f);
        if(MODE==1 && c==C-1) ok = false;
        if(ok){ den[c]+=wt; sig[c]+=wt*v; }
      }
    }
  }
#pragma unroll
  for(int c=0;c<C;c++){
    size_t d = oidx(b,chBase+2*c,i,j);
    out[d]    = den[c];
    out[d+SP] = sig[c]/(den[c]+EPSV);
  }
}

extern "C" void kernel_launch(void* const* d_in, const int* in_sizes, int n_in,
                              void* d_out, int out_size, void* d_ws, size_t ws_size,
                              hipStream_t stream){
  const float* iasi  = (const float*)d_in[0];
  const float* ascat = (const float*)d_in[1];
  const float* hadx  = (const float*)d_in[2];   // (4,8,2,5000)
  const float* hady  = (const float*)d_in[3];   // (4,8,5000)
  const float* icx   = (const float*)d_in[4];   // (8,2,20000)
  const float* icy   = (const float*)d_in[5];   // (8,5,20000)
  const float* slon  = (const float*)d_in[6];
  const float* slat  = (const float*)d_in[7];
  const float* scur  = (const float*)d_in[8];   // (8,2,360,180)
  const float* alon  = (const float*)d_in[9];
  const float* alat  = (const float*)d_in[10];
  const float* acur  = (const float*)d_in[11];  // (8,121,240,13)
  const float* blon  = (const float*)d_in[12];
  const float* blat  = (const float*)d_in[13];
  const float* bcur  = (const float*)d_in[14];  // (8,240,121,12)
  const float* hlon  = (const float*)d_in[15];
  const float* hlat  = (const float*)d_in[16];
  const float* hcur  = (const float*)d_in[17];  // (8,240,121,26)
  const float* igx   = (const float*)d_in[18];  // (8,2,3000)
  const float* igy   = (const float*)d_in[19];  // (8,24,3000)
  const float* elev  = (const float*)d_in[20];  // (8,1,480,242)
  const float* clim  = (const float*)d_in[21];  // (8,24,240,121)
  const float* aux   = (const float*)d_in[22];  // (8,5)
  const float* ls    = (const float*)d_in[23];
  float* out = (float*)d_out;
  dim3 tb(256);
  auto nb = [](long long n){ return dim3((unsigned)((n+255)/256)); };

  // zero off-grid channel ranges (HadISD 11-28 incl ICOADS, IGRA 83-130)
  kzero_range<<<nb((long long)NB*18*SP),tb,0,stream>>>(out, 11, 18);
  kzero_range<<<nb((long long)NB*48*SP),tb,0,stream>>>(out, 83, 48);

  // channels 0-7 IASI, 8-10 ASCAT
  kresize<8><<<nb((long long)NB*8*SP),tb,0,stream>>>(iasi, out, 0);
  kresize<3><<<nb((long long)NB*3*SP),tb,0,stream>>>(ascat, out, 8);

  // HadISD (4 sets of C=1) -> channels 11..18
  for(int c=0;c<4;c++){
    koff<1><<<nb((long long)NB*5000),tb,0,stream>>>(hadx + c*80000, hadx + c*80000 + 5000, 10000,
                                                    hady + c*40000, 5000, 11+2*c, ls, out);
  }
  // ICOADS C=5 -> channels 19..28
  koff<5><<<nb((long long)NB*20000),tb,0,stream>>>(icx, icx+20000, 40000, icy, 20000, 19, ls, out);
  // IGRA C=24 -> channels 83..130
  koff<24><<<nb((long long)NB*3000),tb,0,stream>>>(igx, igx+3000, 6000, igy, 3000, 83, ls, out);

  kdiv<<<nb((long long)NB*4*SP),tb,0,stream>>>(out, 11, 4);
  kdiv<<<nb((long long)NB*5*SP),tb,0,stream>>>(out, 19, 5);
  kdiv<<<nb((long long)NB*24*SP),tb,0,stream>>>(out, 83, 24);

  // on-grid: GRIDSAT ch29, AMSU-A ch33, AMSU-B ch59, HIRS ch131
  kon<2,0><<<nb((long long)NB*SP),tb,0,stream>>>(slon, slat, scur, 360, 180, 29, ls, out);
  kon<13,1><<<nb((long long)NB*SP),tb,0,stream>>>(alon, alat, acur, 240, 121, 33, ls, out);
  kon<12,2><<<nb((long long)NB*SP),tb,0,stream>>>(blon, blat, bcur, 240, 121, 59, ls, out);
  kon<26,2><<<nb((long long)NB*SP),tb,0,stream>>>(hlon, hlat, hcur, 240, 121, 131, ls, out);

  // elevation ch183, climatology 184-207, aux 208-212
  kelev<<<nb((long long)NB*SP),tb,0,stream>>>(elev, out);
  kclim<<<nb((long long)NB*29*SP),tb,0,stream>>>(clim, aux, out);
}

// Round 2
// 1059.572 us; speedup vs baseline: 2.1446x; 2.1446x over previous
//
#include <hip/hip_runtime.h>
#include <cmath>

#define GXN 240
#define GYN 121
#define SP  29040   // GXN*GYN
#define NB  8
#define NCH 213
#define EPSV 1e-6f
#define DMAXF 7.75f   // sqrt(2*30) * ls  -> weight >= ~9.4e-14 kept
#define ACLIP -30.0f

__device__ __forceinline__ float gxv(int i){ return (float)i * (1.0f/239.0f); }
__device__ __forceinline__ float gyv(int j){ return -0.25f + (float)j * (1.0f/240.0f); }
__device__ __forceinline__ size_t oidx(int b,int c,int i,int j){
  return (((size_t)b*NCH + c)*GXN + i)*GYN + j;
}
__device__ __forceinline__ int binx(float x){
  int i = (int)floorf(x*239.0f + 0.5f);
  return i<0?0:(i>239?239:i);
}
__device__ __forceinline__ int biny(float y){
  int j = (int)floorf((y+0.25f)*240.0f + 0.5f);
  return j<0?0:(j>120?120:j);
}
__device__ __forceinline__ int lbnd(const float* a, int n, float v){
  int lo=0, hi=n;
  while(lo<hi){ int m=(lo+hi)>>1; if(a[m]<v) lo=m+1; else hi=m; }
  return lo;
}
__device__ __forceinline__ int ubnd(const float* a, int n, float v){
  int lo=0, hi=n;
  while(lo<hi){ int m=(lo+hi)>>1; if(a[m]<=v) lo=m+1; else hi=m; }
  return lo;
}

// ====================== binning pipeline (off-grid) =========================
__global__ void kzero_i(int* __restrict__ p, int n){
  int i = blockIdx.x*blockDim.x + threadIdx.x;
  if(i<n) p[i]=0;
}

// count points per (virtual-batch, cell)
__global__ void kcount(const float* __restrict__ pbase, int pstride, int N, int nvb,
                       int* __restrict__ counts){
  int idx = blockIdx.x*blockDim.x + threadIdx.x;
  if(idx >= nvb*N) return;
  int vb = idx/N, n = idx%N;
  float x  = pbase[(size_t)vb*pstride + n];
  float yy = pbase[(size_t)vb*pstride + N + n];
  atomicAdd(counts + vb*SP + binx(x)*GYN + biny(yy), 1);
}

// exclusive scan, stage 1: per-1024-element block (256 thr x 4)
__global__ void kscan1(const int* __restrict__ in, int* __restrict__ part,
                       int* __restrict__ bsum, int n){
  __shared__ int ts[256];
  int t = threadIdx.x;
  int base = blockIdx.x*1024 + t*4;
  int v0=0,v1=0,v2=0,v3=0;
  if(base+0<n) v0=in[base+0];
  if(base+1<n) v1=in[base+1];
  if(base+2<n) v2=in[base+2];
  if(base+3<n) v3=in[base+3];
  ts[t]=v0+v1+v2+v3; __syncthreads();
  for(int off=1; off<256; off<<=1){
    int x = (t>=off)? ts[t-off] : 0; __syncthreads();
    ts[t]+=x; __syncthreads();
  }
  int ex = (t==0)? 0 : ts[t-1];
  if(base+0<n) part[base+0]=ex;
  if(base+1<n) part[base+1]=ex+v0;
  if(base+2<n) part[base+2]=ex+v0+v1;
  if(base+3<n) part[base+3]=ex+v0+v1+v2;
  if(t==255) bsum[blockIdx.x]=ts[255];
}

// stage 2: single block scans block sums (n <= 1024)
__global__ void kscan2(int* __restrict__ b, int n){
  __shared__ int ts[256];
  int t = threadIdx.x;
  int base = t*4;
  int v0=0,v1=0,v2=0,v3=0;
  if(base+0<n) v0=b[base+0];
  if(base+1<n) v1=b[base+1];
  if(base+2<n) v2=b[base+2];
  if(base+3<n) v3=b[base+3];
  ts[t]=v0+v1+v2+v3; __syncthreads();
  for(int off=1; off<256; off<<=1){
    int x = (t>=off)? ts[t-off] : 0; __syncthreads();
    ts[t]+=x; __syncthreads();
  }
  int ex = (t==0)? 0 : ts[t-1];
  if(base+0<n) b[base+0]=ex;
  if(base+1<n) b[base+1]=ex+v0;
  if(base+2<n) b[base+2]=ex+v0+v1;
  if(base+3<n) b[base+3]=ex+v0+v1+v2;
}

// stage 3: combine -> offs, cursor
__global__ void kscan3(const int* __restrict__ part, const int* __restrict__ bsum,
                       int* __restrict__ offs, int* __restrict__ cursor, int n){
  int i = blockIdx.x*blockDim.x + threadIdx.x;
  if(i>=n) return;
  int v = part[i] + bsum[i>>10];
  offs[i]=v; cursor[i]=v;
}

// fill per-cell point index lists
__global__ void kfill(const float* __restrict__ pbase, int pstride, int N, int nvb,
                      int* __restrict__ cursor, int* __restrict__ pidx){
  int idx = blockIdx.x*blockDim.x + threadIdx.x;
  if(idx >= nvb*N) return;
  int vb = idx/N, n = idx%N;
  float x  = pbase[(size_t)vb*pstride + n];
  float yy = pbase[(size_t)vb*pstride + N + n];
  int pos = atomicAdd(cursor + vb*SP + binx(x)*GYN + biny(yy), 1);
  pidx[pos] = n;
}

// gather: one thread per (vb, i, j) output cell; writes finalized den & sig
template<int C>
__global__ void kgoff(const float* __restrict__ pbase, int pstride,
                      const float* __restrict__ y, int N, int nvb, int chBase,
                      const float* __restrict__ lsp,
                      const int* __restrict__ offs, const int* __restrict__ counts,
                      const int* __restrict__ pidx, float* __restrict__ out){
  int idx = blockIdx.x*blockDim.x + threadIdx.x;
  if(idx >= nvb*SP) return;
  int vb = idx/SP; int cell = idx%SP; int i = cell/GYN; int j = cell%GYN;
  int b = vb & 7; int set = vb >> 3;    // virtual batch = set*8 + b
  float ls = lsp[0];
  float inv2 = 0.5f/(ls*ls);
  float dmax = DMAXF*ls;
  int rbx = (int)ceilf(dmax*239.0f + 0.5f);
  int rby = (int)ceilf(dmax*240.0f + 0.5f);
  float gi = gxv(i), gj = gyv(j);
  float den[C], sig[C];
#pragma unroll
  for(int c=0;c<C;c++){ den[c]=0.f; sig[c]=0.f; }
  int ilo = i-rbx; if(ilo<0) ilo=0;
  int ihi = i+rbx; if(ihi>GXN-1) ihi=GXN-1;
  int jlo = j-rby; if(jlo<0) jlo=0;
  int jhi = j+rby; if(jhi>GYN-1) jhi=GYN-1;
  const float* px = pbase + (size_t)vb*pstride;
  const float* py = px + N;
  for(int bi=ilo; bi<=ihi; bi++){
    for(int bj=jlo; bj<=jhi; bj++){
      int cb = vb*SP + bi*GYN + bj;
      int s0 = offs[cb], cnt = counts[cb];
      for(int t=0; t<cnt; t++){
        int n = pidx[s0+t];
        float dx = px[n]-gi, dy = py[n]-gj;
        float a = -(dx*dx + dy*dy)*inv2;
        if(a < ACLIP) continue;
        float wt = expf(a);
#pragma unroll
        for(int c=0;c<C;c++){
          float v = y[((size_t)vb*C + c)*N + n];
          if(isfinite(v)){ den[c]+=wt; sig[c]+=wt*v; }
        }
      }
    }
  }
#pragma unroll
  for(int c=0;c<C;c++){
    size_t d = oidx(b, chBase + set*2*C + 2*c, i, j);
    out[d]    = den[c];
    out[d+SP] = sig[c]/(den[c]+EPSV);
  }
}

// ---------------- IASI / ASCAT: nan->0, nearest resize, flip lat ------------
template<int C>
__global__ void kresize(const float* __restrict__ src, float* __restrict__ out, int chBase){
  int idx = blockIdx.x*blockDim.x + threadIdx.x;
  if(idx >= NB*C*SP) return;
  int j = idx%GYN; int i=(idx/GYN)%GXN; int c=(idx/SP)%C; int b=idx/(SP*C);
  int hi = i>>1;                       // (i*120)//240
  int wi = ((120 - j)*60)/121;         // flip j then (j'*60)//121
  float v = src[((b*120 + hi)*60 + wi)*C + c];
  if(!isfinite(v)) v = isnan(v) ? 0.f : (v>0.f? 3.4028235e38f : -3.4028235e38f);
  out[oidx(b,chBase+c,i,j)] = v;
}

// ---------------- elevation: out[b,183,i,j] = era5[b,0,2i,241-2j] -----------
__global__ void kelev(const float* __restrict__ e, float* __restrict__ out){
  int idx = blockIdx.x*blockDim.x + threadIdx.x;
  if(idx>=NB*SP) return;
  int j=idx%GYN; int i=(idx/GYN)%GXN; int b=idx/SP;
  out[oidx(b,183,i,j)] = e[(b*480 + 2*i)*242 + (241 - 2*j)];
}

// ---------------- climatology copy + aux_time broadcast ---------------------
__global__ void kclim(const float* __restrict__ clim, const float* __restrict__ aux,
                      float* __restrict__ out){
  int idx = blockIdx.x*blockDim.x + threadIdx.x;
  if(idx >= NB*29*SP) return;
  int j=idx%GYN; int i=(idx/GYN)%GXN; int c=(idx/SP)%29; int b=idx/(SP*29);
  float v;
  if(c<24) v = clim[(((size_t)b*24 + c)*GXN + i)*GYN + j];
  else     v = aux[b*5 + (c-24)];
  out[oidx(b,184+c,i,j)] = v;
}

// ---------------- on-grid setconv: gather per output cell -------------------
// MODE 0: val = src[((b*C+c)*H + h)*W + w], mask = isfinite            (GRIDSAT)
// MODE 1: val = src[((b*W+w)*H + h)*C + c], mask = fin && v!=0 && c!=C-1 (AMSU-A)
// MODE 2: val = src[((b*H+h)*W + w)*C + c], mask = fin && v!=0          (AMSU-B/HIRS)
template<int C, int MODE>
__global__ void kon(const float* __restrict__ xlon, const float* __restrict__ xlat,
                    const float* __restrict__ src, int H, int W, int chBase,
                    const float* __restrict__ lsp, float* __restrict__ out){
  int idx = blockIdx.x*blockDim.x + threadIdx.x;
  if(idx >= NB*SP) return;
  int j=idx%GYN; int i=(idx/GYN)%GXN; int b=idx/SP;
  float ls = lsp[0];
  float inv2 = 0.5f/(ls*ls);
  float dmax = DMAXF*ls;
  float gi = gxv(i), gj = gyv(j);
  const float* lon = xlon + b*H;
  const float* lat = xlat + b*W;
  int hlo = lbnd(lon,H,gi-dmax), hhi = ubnd(lon,H,gi+dmax);
  int wlo = lbnd(lat,W,gj-dmax), whi = ubnd(lat,W,gj+dmax);
  float den[C], sig[C];
#pragma unroll
  for(int c=0;c<C;c++){ den[c]=0.f; sig[c]=0.f; }
  for(int h=hlo; h<hhi; h++){
    float dx = lon[h]-gi;
    float ax = -dx*dx*inv2;
    if(ax < ACLIP) continue;
    for(int w=wlo; w<whi; w++){
      float dy = lat[w]-gj;
      float a = ax - dy*dy*inv2;
      if(a < ACLIP) continue;
      float wt = expf(a);
      const float* s;
      if(MODE==0)      s = src + ((size_t)b*C*H + h)*W + w;
      else if(MODE==1) s = src + (((size_t)b*W + w)*H + h)*C;
      else             s = src + (((size_t)b*H + h)*W + w)*C;
#pragma unroll
      for(int c=0;c<C;c++){
        float v = (MODE==0) ? s[(size_t)c*H*W] : s[c];
        bool ok = isfinite(v);
        if(MODE>=1) ok = ok && (v!=0.0f);
        if(MODE==1 && c==C-1) ok = false;
        if(ok){ den[c]+=wt; sig[c]+=wt*v; }
      }
    }
  }
#pragma unroll
  for(int c=0;c<C;c++){
    size_t d = oidx(b,chBase+2*c,i,j);
    out[d]    = den[c];
    out[d+SP] = sig[c]/(den[c]+EPSV);
  }
}

extern "C" void kernel_launch(void* const* d_in, const int* in_sizes, int n_in,
                              void* d_out, int out_size, void* d_ws, size_t ws_size,
                              hipStream_t stream){
  const float* iasi  = (const float*)d_in[0];
  const float* ascat = (const float*)d_in[1];
  const float* hadx  = (const float*)d_in[2];   // (4,8,2,5000)
  const float* hady  = (const float*)d_in[3];   // (4,8,5000)
  const float* icx   = (const float*)d_in[4];   // (8,2,20000)
  const float* icy   = (const float*)d_in[5];   // (8,5,20000)
  const float* slon  = (const float*)d_in[6];
  const float* slat  = (const float*)d_in[7];
  const float* scur  = (const float*)d_in[8];   // (8,2,360,180)
  const float* alon  = (const float*)d_in[9];
  const float* alat  = (const float*)d_in[10];
  const float* acur  = (const float*)d_in[11];  // (8,121,240,13)
  const float* blon  = (const float*)d_in[12];
  const float* blat  = (const float*)d_in[13];
  const float* bcur  = (const float*)d_in[14];  // (8,240,121,12)
  const float* hlon  = (const float*)d_in[15];
  const float* hlat  = (const float*)d_in[16];
  const float* hcur  = (const float*)d_in[17];  // (8,240,121,26)
  const float* igx   = (const float*)d_in[18];  // (8,2,3000)
  const float* igy   = (const float*)d_in[19];  // (8,24,3000)
  const float* elev  = (const float*)d_in[20];  // (8,1,480,242)
  const float* clim  = (const float*)d_in[21];  // (8,24,240,121)
  const float* aux   = (const float*)d_in[22];  // (8,5)
  const float* ls    = (const float*)d_in[23];
  float* out = (float*)d_out;
  dim3 tb(256);
  auto nb = [](long long n){ return dim3((unsigned)((n+255)/256)); };

  // workspace layout (ints), reused sequentially across the 3 off-grid datasets
  const int NMAX = 32*SP;               // 929280 (HadISD fused: 32 virtual batches)
  int* counts = (int*)d_ws;
  int* offs   = counts + NMAX;
  int* cursor = offs   + NMAX;
  int* bsum   = cursor + NMAX;
  int* pidx   = bsum   + 1024;          // up to 160000 point slots
  // requires ws_size >= ~11.8 MB

  // run one binning+gather pipeline
  auto scan_pipeline = [&](const float* pbase, int pstride, const float* y,
                           int N, int nvb, int chBase, int C){
    int ncell = nvb*SP;
    int nblk  = (ncell + 1023)/1024;
    kzero_i<<<nb(ncell),tb,0,stream>>>(counts, ncell);
    kcount <<<nb((long long)nvb*N),tb,0,stream>>>(pbase, pstride, N, nvb, counts);
    kscan1 <<<dim3(nblk),tb,0,stream>>>(counts, offs, bsum, ncell);
    kscan2 <<<dim3(1),tb,0,stream>>>(bsum, nblk);
    kscan3 <<<nb(ncell),tb,0,stream>>>(offs, bsum, offs, cursor, ncell);
    kfill  <<<nb((long long)nvb*N),tb,0,stream>>>(pbase, pstride, N, nvb, cursor, pidx);
    if(C==1)       kgoff<1> <<<nb(ncell),tb,0,stream>>>(pbase,pstride,y,N,nvb,chBase,ls,offs,counts,pidx,out);
    else if(C==5)  kgoff<5> <<<nb(ncell),tb,0,stream>>>(pbase,pstride,y,N,nvb,chBase,ls,offs,counts,pidx,out);
    else           kgoff<24><<<nb(ncell),tb,0,stream>>>(pbase,pstride,y,N,nvb,chBase,ls,offs,counts,pidx,out);
  };

  // channels 0-7 IASI, 8-10 ASCAT
  kresize<8><<<nb((long long)NB*8*SP),tb,0,stream>>>(iasi, out, 0);
  kresize<3><<<nb((long long)NB*3*SP),tb,0,stream>>>(ascat, out, 8);

  // HadISD: 4 sets fused as 32 virtual batches, C=1 -> channels 11..18
  scan_pipeline(hadx, 10000, hady, 5000, 32, 11, 1);
  // ICOADS C=5 -> channels 19..28
  scan_pipeline(icx, 40000, icy, 20000, 8, 19, 5);
  // IGRA C=24 -> channels 83..130
  scan_pipeline(igx, 6000, igy, 3000, 8, 83, 24);

  // on-grid: GRIDSAT ch29, AMSU-A ch33, AMSU-B ch59, HIRS ch131
  kon<2,0> <<<nb((long long)NB*SP),tb,0,stream>>>(slon, slat, scur, 360, 180, 29, ls, out);
  kon<13,1><<<nb((long long)NB*SP),tb,0,stream>>>(alon, alat, acur, 240, 121, 33, ls, out);
  kon<12,2><<<nb((long long)NB*SP),tb,0,stream>>>(blon, blat, bcur, 240, 121, 59, ls, out);
  kon<26,2><<<nb((long long)NB*SP),tb,0,stream>>>(hlon, hlat, hcur, 240, 121, 131, ls, out);

  // elevation ch183, climatology 184-207, aux 208-212
  kelev<<<nb((long long)NB*SP),tb,0,stream>>>(elev, out);
  kclim<<<nb((long long)NB*29*SP),tb,0,stream>>>(clim, aux, out);
}

// Round 3
// 747.832 us; speedup vs baseline: 3.0386x; 1.4169x over previous
//
#include <hip/hip_runtime.h>
#include <cmath>

#define GXN 240
#define GYN 121
#define SP  29040   // GXN*GYN
#define NB  8
#define NCH 213
#define EPSV 1e-6f
#define DMAXF 7.75f   // sqrt(2*30) * ls  -> weight >= ~9.4e-14 kept
#define ACLIP -30.0f

// unified off-grid point space: HadISD(32 vb x 5000) + ICOADS(8 x 20000) + IGRA(8 x 3000)
#define P_HAD   160000
#define P_ICO   160000
#define P_IGRA  24000
#define PT_TOT  344000
#define VB_TOT  48
#define NCELL   (VB_TOT*SP)   // 1,393,920

__device__ __forceinline__ float gxv(int i){ return (float)i * (1.0f/239.0f); }
__device__ __forceinline__ float gyv(int j){ return -0.25f + (float)j * (1.0f/240.0f); }
__device__ __forceinline__ size_t oidx(int b,int c,int i,int j){
  return (((size_t)b*NCH + c)*GXN + i)*GYN + j;
}
__device__ __forceinline__ int binx(float x){
  int i = (int)floorf(x*239.0f + 0.5f);
  return i<0?0:(i>239?239:i);
}
__device__ __forceinline__ int biny(float y){
  int j = (int)floorf((y+0.25f)*240.0f + 0.5f);
  return j<0?0:(j>120?120:j);
}
__device__ __forceinline__ int lbnd(const float* a, int n, float v){
  int lo=0, hi=n;
  while(lo<hi){ int m=(lo+hi)>>1; if(a[m]<v) lo=m+1; else hi=m; }
  return lo;
}
__device__ __forceinline__ int ubnd(const float* a, int n, float v){
  int lo=0, hi=n;
  while(lo<hi){ int m=(lo+hi)>>1; if(a[m]<=v) lo=m+1; else hi=m; }
  return lo;
}

// map unified point idx -> (dataset, vb, n, cell)
struct PtLoc { int ds, vb, n; float x, y; };
__device__ __forceinline__ PtLoc ptloc(int idx, const float* hadx, const float* icx, const float* igx){
  PtLoc p;
  if(idx < P_HAD){
    p.ds=0; p.vb=idx/5000; p.n=idx%5000;
    p.x = hadx[(size_t)p.vb*10000 + p.n];
    p.y = hadx[(size_t)p.vb*10000 + 5000 + p.n];
  } else if(idx < P_HAD + P_ICO){
    int t = idx - P_HAD; p.ds=1; p.vb=t/20000; p.n=t%20000;
    p.x = icx[(size_t)p.vb*40000 + p.n];
    p.y = icx[(size_t)p.vb*40000 + 20000 + p.n];
  } else {
    int t = idx - (P_HAD+P_ICO); p.ds=2; p.vb=t/3000; p.n=t%3000;
    p.x = igx[(size_t)p.vb*6000 + p.n];
    p.y = igx[(size_t)p.vb*6000 + 3000 + p.n];
  }
  return p;
}
__device__ __forceinline__ int vbglobal(const PtLoc& p){
  return (p.ds==0)? p.vb : (p.ds==1? 32+p.vb : 40+p.vb);
}

// ====================== binning pipeline ====================================
__global__ void kzero_i(int* __restrict__ p, int n){
  int i = blockIdx.x*blockDim.x + threadIdx.x;
  if(i<n) p[i]=0;
}

__global__ void kcount(const float* __restrict__ hadx, const float* __restrict__ icx,
                       const float* __restrict__ igx, int* __restrict__ counts){
  int idx = blockIdx.x*blockDim.x + threadIdx.x;
  if(idx >= PT_TOT) return;
  PtLoc p = ptloc(idx, hadx, icx, igx);
  atomicAdd(counts + vbglobal(p)*SP + binx(p.x)*GYN + biny(p.y), 1);
}

// scan stage 1: 1024 elems per block (256 thr x 4)
__global__ void kscan1(const int* __restrict__ in, int* __restrict__ part,
                       int* __restrict__ bsum, int n){
  __shared__ int ts[256];
  int t = threadIdx.x;
  int base = blockIdx.x*1024 + t*4;
  int v0=0,v1=0,v2=0,v3=0;
  if(base+0<n) v0=in[base+0];
  if(base+1<n) v1=in[base+1];
  if(base+2<n) v2=in[base+2];
  if(base+3<n) v3=in[base+3];
  ts[t]=v0+v1+v2+v3; __syncthreads();
  for(int off=1; off<256; off<<=1){
    int x = (t>=off)? ts[t-off] : 0; __syncthreads();
    ts[t]+=x; __syncthreads();
  }
  int ex = (t==0)? 0 : ts[t-1];
  if(base+0<n) part[base+0]=ex;
  if(base+1<n) part[base+1]=ex+v0;
  if(base+2<n) part[base+2]=ex+v0+v1;
  if(base+3<n) part[base+3]=ex+v0+v1+v2;
  if(t==255) bsum[blockIdx.x]=ts[255];
}

// scan stage 2: single block, up to 4096 elems (256 thr x 16)
__global__ void kscan2(int* __restrict__ b, int n){
  __shared__ int ts[256];
  int t = threadIdx.x;
  int v[16]; int s=0;
#pragma unroll
  for(int k=0;k<16;k++){ int p=t*16+k; v[k] = (p<n)? b[p] : 0; s+=v[k]; }
  ts[t]=s; __syncthreads();
  for(int off=1; off<256; off<<=1){
    int x = (t>=off)? ts[t-off] : 0; __syncthreads();
    ts[t]+=x; __syncthreads();
  }
  int run = (t==0)? 0 : ts[t-1];
#pragma unroll
  for(int k=0;k<16;k++){ int p=t*16+k; if(p<n) b[p]=run; run+=v[k]; }
}

// stage 3: combine -> offs (+sentinel), cursor (reuses counts array)
__global__ void kscan3(const int* __restrict__ part, const int* __restrict__ bsum,
                       int* __restrict__ offs, int* __restrict__ cursor, int n){
  int i = blockIdx.x*blockDim.x + threadIdx.x;
  if(i==0) offs[n] = PT_TOT;
  if(i>=n) return;
  int v = part[i] + bsum[i>>10];
  offs[i]=v; cursor[i]=v;
}

// pack records: (x, y, v0..vC-1) contiguous per bin
__global__ void kpack(const float* __restrict__ hadx, const float* __restrict__ icx,
                      const float* __restrict__ igx,
                      const float* __restrict__ hady, const float* __restrict__ icy,
                      const float* __restrict__ igy,
                      int* __restrict__ cursor,
                      float* __restrict__ had_rec, float* __restrict__ ico_rec,
                      float* __restrict__ igra_rec){
  int idx = blockIdx.x*blockDim.x + threadIdx.x;
  if(idx >= PT_TOT) return;
  PtLoc p = ptloc(idx, hadx, icx, igx);
  int cell = vbglobal(p)*SP + binx(p.x)*GYN + biny(p.y);
  int pos = atomicAdd(cursor + cell, 1);
  if(p.ds==0){
    float* r = had_rec + (size_t)pos*4;           // pos in [0,160000)
    r[0]=p.x; r[1]=p.y;
    r[2]=hady[(size_t)p.vb*5000 + p.n];
  } else if(p.ds==1){
    float* r = ico_rec + (size_t)(pos - P_HAD)*8;
    r[0]=p.x; r[1]=p.y;
#pragma unroll
    for(int c=0;c<5;c++) r[2+c]=icy[((size_t)p.vb*5 + c)*20000 + p.n];
  } else {
    float* r = igra_rec + (size_t)(pos - P_HAD - P_ICO)*28;
    r[0]=p.x; r[1]=p.y;
#pragma unroll
    for(int c=0;c<24;c++) r[2+c]=igy[((size_t)p.vb*24 + c)*3000 + p.n];
  }
}

// gather from packed records; one thread per (vb, cell); row-contiguous record runs
template<int C, int RS>
__global__ void kgoff(const float* __restrict__ rec, const int* __restrict__ offs,
                      int vbBase, int dsBase, int nvb, int chBase,
                      const float* __restrict__ lsp, float* __restrict__ out){
  int idx = blockIdx.x*blockDim.x + threadIdx.x;
  if(idx >= nvb*SP) return;
  int vb = idx/SP; int cell = idx%SP; int i = cell/GYN; int j = cell%GYN;
  int b = vb & 7; int set = vb >> 3;
  int vbG = vbBase + vb;
  float ls = lsp[0];
  float inv2 = 0.5f/(ls*ls);
  float dmax = DMAXF*ls;
  int rbx = (int)floorf(dmax*239.0f + 0.5f);  // exact: bin at rbx+1 is always out of range
  int rby = (int)floorf(dmax*240.0f + 0.5f);
  float gi = gxv(i), gj = gyv(j);
  float den[C], sig[C];
#pragma unroll
  for(int c=0;c<C;c++){ den[c]=0.f; sig[c]=0.f; }
  int ilo = i-rbx; if(ilo<0) ilo=0;
  int ihi = i+rbx; if(ihi>GXN-1) ihi=GXN-1;
  int jlo = j-rby; if(jlo<0) jlo=0;
  int jhi = j+rby; if(jhi>GYN-1) jhi=GYN-1;
  int jspan = jhi - jlo;
  for(int bi=ilo; bi<=ihi; bi++){
    int cb0 = vbG*SP + bi*GYN + jlo;
    int s = offs[cb0] - dsBase;
    int e = offs[cb0 + jspan + 1] - dsBase;
    for(int t=s; t<e; t++){
      const float* r = rec + (size_t)t*RS;
      float dx = r[0]-gi, dy = r[1]-gj;
      float a = -(dx*dx + dy*dy)*inv2;
      if(a < ACLIP) continue;
      float wt = expf(a);
#pragma unroll
      for(int c=0;c<C;c++){
        float v = r[2+c];
        if(isfinite(v)){ den[c]+=wt; sig[c]+=wt*v; }
      }
    }
  }
#pragma unroll
  for(int c=0;c<C;c++){
    size_t d = oidx(b, chBase + set*2*C + 2*c, i, j);
    out[d]    = den[c];
    out[d+SP] = sig[c]/(den[c]+EPSV);
  }
}

// ---------------- fused trivial copies: IASI, ASCAT, elev, clim, aux --------
__global__ void kcopy(const float* __restrict__ iasi, const float* __restrict__ ascat,
                      const float* __restrict__ elev, const float* __restrict__ clim,
                      const float* __restrict__ aux, float* __restrict__ out){
  int idx = blockIdx.x*blockDim.x + threadIdx.x;
  if(idx >= NB*41*SP) return;
  int j = idx%GYN; int i=(idx/GYN)%GXN; int cc=(idx/SP)%41; int b=idx/(SP*41);
  float v; int oc;
  if(cc < 8){
    int hi = i>>1, wi = ((120 - j)*60)/121;
    v = iasi[((b*120 + hi)*60 + wi)*8 + cc];
    if(!isfinite(v)) v = isnan(v) ? 0.f : (v>0.f? 3.4028235e38f : -3.4028235e38f);
    oc = cc;
  } else if(cc < 11){
    int hi = i>>1, wi = ((120 - j)*60)/121;
    v = ascat[((b*120 + hi)*60 + wi)*3 + (cc-8)];
    if(!isfinite(v)) v = isnan(v) ? 0.f : (v>0.f? 3.4028235e38f : -3.4028235e38f);
    oc = cc;
  } else if(cc == 11){
    v = elev[(b*480 + 2*i)*242 + (241 - 2*j)];
    oc = 183;
  } else if(cc < 36){
    int c = cc-12;
    v = clim[(((size_t)b*24 + c)*GXN + i)*GYN + j];
    oc = 184 + c;
  } else {
    v = aux[b*5 + (cc-36)];
    oc = 208 + (cc-36);
  }
  out[oidx(b,oc,i,j)] = v;
}

// ---------------- on-grid setconv: gather per output cell -------------------
// MODE 0: val = src[((b*C+c)*H + h)*W + w], mask = isfinite            (GRIDSAT)
// MODE 1: val = src[((b*W+w)*H + h)*C + c], mask = fin && v!=0 && c!=C-1 (AMSU-A)
// MODE 2: val = src[((b*H+h)*W + w)*C + c], mask = fin && v!=0          (AMSU-B/HIRS)
template<int C, int MODE>
__global__ void kon(const float* __restrict__ xlon, const float* __restrict__ xlat,
                    const float* __restrict__ src, int H, int W, int chBase,
                    const float* __restrict__ lsp, float* __restrict__ out){
  int idx = blockIdx.x*blockDim.x + threadIdx.x;
  if(idx >= NB*SP) return;
  int j=idx%GYN; int i=(idx/GYN)%GXN; int b=idx/SP;
  float ls = lsp[0];
  float inv2 = 0.5f/(ls*ls);
  float dmax = DMAXF*ls;
  float gi = gxv(i), gj = gyv(j);
  const float* lon = xlon + b*H;
  const float* lat = xlat + b*W;
  int hlo = lbnd(lon,H,gi-dmax), hhi = ubnd(lon,H,gi+dmax);
  int wlo = lbnd(lat,W,gj-dmax), whi = ubnd(lat,W,gj+dmax);
  float den[C], sig[C];
#pragma unroll
  for(int c=0;c<C;c++){ den[c]=0.f; sig[c]=0.f; }
  for(int h=hlo; h<hhi; h++){
    float dx = lon[h]-gi;
    float ax = -dx*dx*inv2;
    if(ax < ACLIP) continue;
    for(int w=wlo; w<whi; w++){
      float dy = lat[w]-gj;
      float a = ax - dy*dy*inv2;
      if(a < ACLIP) continue;
      float wt = expf(a);
      const float* s;
      if(MODE==0)      s = src + ((size_t)b*C*H + h)*W + w;
      else if(MODE==1) s = src + (((size_t)b*W + w)*H + h)*C;
      else             s = src + (((size_t)b*H + h)*W + w)*C;
#pragma unroll
      for(int c=0;c<C;c++){
        float v = (MODE==0) ? s[(size_t)c*H*W] : s[c];
        bool ok = isfinite(v);
        if(MODE>=1) ok = ok && (v!=0.0f);
        if(MODE==1 && c==C-1) ok = false;
        if(ok){ den[c]+=wt; sig[c]+=wt*v; }
      }
    }
  }
#pragma unroll
  for(int c=0;c<C;c++){
    size_t d = oidx(b,chBase+2*c,i,j);
    out[d]    = den[c];
    out[d+SP] = sig[c]/(den[c]+EPSV);
  }
}

extern "C" void kernel_launch(void* const* d_in, const int* in_sizes, int n_in,
                              void* d_out, int out_size, void* d_ws, size_t ws_size,
                              hipStream_t stream){
  const float* iasi  = (const float*)d_in[0];
  const float* ascat = (const float*)d_in[1];
  const float* hadx  = (const float*)d_in[2];   // (4,8,2,5000)
  const float* hady  = (const float*)d_in[3];   // (4,8,5000)
  const float* icx   = (const float*)d_in[4];   // (8,2,20000)
  const float* icy   = (const float*)d_in[5];   // (8,5,20000)
  const float* slon  = (const float*)d_in[6];
  const float* slat  = (const float*)d_in[7];
  const float* scur  = (const float*)d_in[8];   // (8,2,360,180)
  const float* alon  = (const float*)d_in[9];
  const float* alat  = (const float*)d_in[10];
  const float* acur  = (const float*)d_in[11];  // (8,121,240,13)
  const float* blon  = (const float*)d_in[12];
  const float* blat  = (const float*)d_in[13];
  const float* bcur  = (const float*)d_in[14];  // (8,240,121,12)
  const float* hlon  = (const float*)d_in[15];
  const float* hlat  = (const float*)d_in[16];
  const float* hcur  = (const float*)d_in[17];  // (8,240,121,26)
  const float* igx   = (const float*)d_in[18];  // (8,2,3000)
  const float* igy   = (const float*)d_in[19];  // (8,24,3000)
  const float* elev  = (const float*)d_in[20];  // (8,1,480,242)
  const float* clim  = (const float*)d_in[21];  // (8,24,240,121)
  const float* aux   = (const float*)d_in[22];  // (8,5)
  const float* ls    = (const float*)d_in[23];
  float* out = (float*)d_out;
  dim3 tb(256);
  auto nb = [](long long n){ return dim3((unsigned)((n+255)/256)); };

  // workspace layout (~21.6 MB)
  int* counts = (int*)d_ws;                 // NCELL (doubles as cursor)
  int* offs   = counts + NCELL;             // NCELL+1
  int* bsum   = offs + NCELL + 1;           // 4096
  float* had_rec  = (float*)(bsum + 4096);  // 160000*4
  float* ico_rec  = had_rec + 640000;       // 160000*8
  float* igra_rec = ico_rec + 1280000;      // 24000*28

  int nblk = (NCELL + 1023)/1024;           // 1362

  // fused trivial channels first (independent)
  kcopy<<<nb((long long)NB*41*SP),tb,0,stream>>>(iasi, ascat, elev, clim, aux, out);

  // unified off-grid binning
  kzero_i<<<nb(NCELL),tb,0,stream>>>(counts, NCELL);
  kcount <<<nb(PT_TOT),tb,0,stream>>>(hadx, icx, igx, counts);
  kscan1 <<<dim3(nblk),tb,0,stream>>>(counts, offs, bsum, NCELL);
  kscan2 <<<dim3(1),tb,0,stream>>>(bsum, nblk);
  kscan3 <<<nb(NCELL),tb,0,stream>>>(offs, bsum, offs, counts, NCELL);
  kpack  <<<nb(PT_TOT),tb,0,stream>>>(hadx, icx, igx, hady, icy, igy,
                                      counts, had_rec, ico_rec, igra_rec);

  // gathers: HadISD ch11 (C=1, 32 vb), ICOADS ch19 (C=5), IGRA ch83 (C=24)
  kgoff<1,4>  <<<nb((long long)32*SP),tb,0,stream>>>(had_rec,  offs,  0, 0,               32, 11, ls, out);
  kgoff<5,8>  <<<nb((long long)NB*SP),tb,0,stream>>>(ico_rec,  offs, 32, P_HAD,            8, 19, ls, out);
  kgoff<24,28><<<nb((long long)NB*SP),tb,0,stream>>>(igra_rec, offs, 40, P_HAD+P_ICO,      8, 83, ls, out);

  // on-grid: GRIDSAT ch29, AMSU-A ch33, AMSU-B ch59, HIRS ch131
  kon<2,0> <<<nb((long long)NB*SP),tb,0,stream>>>(slon, slat, scur, 360, 180, 29, ls, out);
  kon<13,1><<<nb((long long)NB*SP),tb,0,stream>>>(alon, alat, acur, 240, 121, 33, ls, out);
  kon<12,2><<<nb((long long)NB*SP),tb,0,stream>>>(blon, blat, bcur, 240, 121, 59, ls, out);
  kon<26,2><<<nb((long long)NB*SP),tb,0,stream>>>(hlon, hlat, hcur, 240, 121, 131, ls, out);
}